// Round 1
// 3407.192 us; speedup vs baseline: 2.0027x; 2.0027x over previous
//
#include <hip/hip_runtime.h>
#include <math.h>

#define F 128

typedef float floatx4 __attribute__((ext_vector_type(4)));
typedef short shortx8 __attribute__((ext_vector_type(8)));

__device__ __forceinline__ unsigned short f2bf(float f) {
    union { float f; unsigned u; } v; v.f = f;
    unsigned r = (v.u + 0x7FFFu + ((v.u >> 16) & 1u)) >> 16;
    return (unsigned short)r;
}

__device__ __forceinline__ float sigm(float x) { return 1.f / (1.f + __expf(-x)); }

// ---------------------------------------------------------------------------
// C[M,128(:ldC)] = bf16( A[M,128] ) @ bf16( W[128,128] )^T + bias[128] (+ addend[M,128])
// block = 256 threads (4 waves), BM=64 rows, full K=128 staged in LDS.
// ---------------------------------------------------------------------------
__global__ __launch_bounds__(256) void gemm_aw(
    const float* __restrict__ A, const float* __restrict__ W,
    const float* __restrict__ bias, const float* __restrict__ addend,
    float* __restrict__ C, int M, int ldC)
{
    __shared__ unsigned short As[64 * 136];
    __shared__ unsigned short Ws[128 * 136];
    const int tid = threadIdx.x;
    const long base = (long)blockIdx.x * 64;

    for (int it = 0; it < 16; ++it) {
        int fidx = it * 256 + tid;
        int row = fidx >> 5, c4 = (fidx & 31) * 4;
        float4 wv = *(const float4*)&W[row * 128 + c4];
        unsigned short* p = &Ws[row * 136 + c4];
        p[0] = f2bf(wv.x); p[1] = f2bf(wv.y); p[2] = f2bf(wv.z); p[3] = f2bf(wv.w);
    }
    for (int it = 0; it < 8; ++it) {
        int fidx = it * 256 + tid;
        int row = fidx >> 5, c4 = (fidx & 31) * 4;
        long grow = base + row;
        float4 av = make_float4(0.f, 0.f, 0.f, 0.f);
        if (grow < M) av = *(const float4*)&A[grow * 128 + c4];
        unsigned short* p = &As[row * 136 + c4];
        p[0] = f2bf(av.x); p[1] = f2bf(av.y); p[2] = f2bf(av.z); p[3] = f2bf(av.w);
    }
    __syncthreads();

    const int w = tid >> 6, lane = tid & 63;
    const int ml = lane & 15, quad = lane >> 4;
    floatx4 acc[8];
#pragma unroll
    for (int t = 0; t < 8; ++t) acc[t] = (floatx4)(0.f);

    const int arow = (w * 16 + ml) * 136;
#pragma unroll
    for (int kk = 0; kk < 4; ++kk) {
        shortx8 a = *(const shortx8*)&As[arow + kk * 32 + quad * 8];
#pragma unroll
        for (int t = 0; t < 8; ++t) {
            shortx8 b = *(const shortx8*)&Ws[(t * 16 + ml) * 136 + kk * 32 + quad * 8];
            acc[t] = __builtin_amdgcn_mfma_f32_16x16x32_bf16(a, b, acc[t], 0, 0, 0);
        }
    }

#pragma unroll
    for (int t = 0; t < 8; ++t) {
        int gcol = t * 16 + ml;
        float bv = bias[gcol];
#pragma unroll
        for (int r = 0; r < 4; ++r) {
            long grow = base + w * 16 + quad * 4 + r;
            if (grow < M) {
                float v = acc[t][r] + bv;
                if (addend) v += addend[grow * 128 + gcol];
                C[grow * (long)ldC + gcol] = v;
            }
        }
    }
}

// ---------------------------------------------------------------------------
// CSR build: histogram -> 3-kernel exclusive scan -> scatter
// ---------------------------------------------------------------------------
__global__ __launch_bounds__(256) void hist_k(
    const int* __restrict__ ii, int* __restrict__ counts, int E)
{
    int e = blockIdx.x * 256 + threadIdx.x;
    if (e < E) atomicAdd(&counts[ii[e]], 1);
}

// per-block exclusive scan of 1024 elements (4/thread), block totals to bsums
__global__ __launch_bounds__(256) void scan_block(
    const int* __restrict__ counts, int* __restrict__ excl,
    int* __restrict__ bsums, int N)
{
    __shared__ int lds[256];
    int tid = threadIdx.x;
    int base = blockIdx.x * 1024 + tid * 4;
    int v0 = 0, v1 = 0, v2 = 0, v3 = 0;
    if (base + 0 < N) v0 = counts[base + 0];
    if (base + 1 < N) v1 = counts[base + 1];
    if (base + 2 < N) v2 = counts[base + 2];
    if (base + 3 < N) v3 = counts[base + 3];
    int s = v0 + v1 + v2 + v3;
    lds[tid] = s;
    __syncthreads();
    for (int off = 1; off < 256; off <<= 1) {
        int t = (tid >= off) ? lds[tid - off] : 0;
        __syncthreads();
        lds[tid] += t;
        __syncthreads();
    }
    int ebase = lds[tid] - s;
    if (base + 0 < N) excl[base + 0] = ebase;
    if (base + 1 < N) excl[base + 1] = ebase + v0;
    if (base + 2 < N) excl[base + 2] = ebase + v0 + v1;
    if (base + 3 < N) excl[base + 3] = ebase + v0 + v1 + v2;
    if (tid == 255) bsums[blockIdx.x] = lds[255];
}

// single-block exclusive scan of <=512 block sums (in place)
__global__ __launch_bounds__(512) void scan_bsums(int* __restrict__ bsums, int nb)
{
    __shared__ int lds[512];
    int tid = threadIdx.x;
    int v = (tid < nb) ? bsums[tid] : 0;
    lds[tid] = v;
    __syncthreads();
    for (int off = 1; off < 512; off <<= 1) {
        int t = (tid >= off) ? lds[tid - off] : 0;
        __syncthreads();
        lds[tid] += t;
        __syncthreads();
    }
    if (tid < nb) bsums[tid] = lds[tid] - v;
}

__global__ __launch_bounds__(256) void add_off(
    int* __restrict__ row_ptr, const int* __restrict__ bsums,
    int* __restrict__ cursor, int N, int E)
{
    int i = blockIdx.x * 256 + threadIdx.x;
    if (i < N) {
        int v = row_ptr[i] + bsums[i >> 10];
        row_ptr[i] = v;
        cursor[i] = v;
    }
    if (i == N) row_ptr[N] = E;
}

__global__ __launch_bounds__(256) void scatter_csr(
    const int* __restrict__ ii, const int* __restrict__ jj,
    int* __restrict__ cursor, int2* __restrict__ pairs, int E)
{
    int e = blockIdx.x * 256 + threadIdx.x;
    if (e < E) {
        int p = atomicAdd(&cursor[ii[e]], 1);
        pairs[p] = make_int2(e, jj[e]);
    }
}

// ---------------------------------------------------------------------------
// Fused per-node aggregation (replaces edge_pass1 + edge_pass2 agg + col_stats(msg)):
// per node i (32 lanes, float4/lane):
//   gi = G[i].s0 (loaded once)
//   for e in csr[i]: m = msg[e] + gi + G[j].s1 ; msg[e] = m ;
//                    ss += sigm(m) ; ag += sigm(m)*G[j].s2 ;
//                    st1 += m ; st2 += m*m        (BN stats fused)
//   agg[i] = ag / (ss + 1e-9)                      (sig_sum never materialized)
// Block stats: LDS reduce over 8 subgroups -> 256 global atomics per block.
// ---------------------------------------------------------------------------
__global__ __launch_bounds__(256) void node_gather(
    const int* __restrict__ row_ptr, const int2* __restrict__ pairs,
    const float* __restrict__ G, float* __restrict__ msg,
    float* __restrict__ agg, float* __restrict__ stats, int Nn)
{
    const int sub = threadIdx.x >> 5, lane = threadIdx.x & 31;
    const int c = lane * 4;
    float st1x = 0.f, st1y = 0.f, st1z = 0.f, st1w = 0.f;
    float st2x = 0.f, st2y = 0.f, st2z = 0.f, st2w = 0.f;

    for (long n = (long)blockIdx.x * 8 + sub; n < Nn; n += (long)gridDim.x * 8) {
        float4 gi = *(const float4*)&G[n * 384 + c];
        float ssx = 0.f, ssy = 0.f, ssz = 0.f, ssw = 0.f;
        float agx = 0.f, agy = 0.f, agz = 0.f, agw = 0.f;
        int e0 = row_ptr[n], e1 = row_ptr[n + 1];
        for (int e = e0; e < e1; ++e) {
            int2 pj = pairs[e];
            long eo = pj.x, j = pj.y;
            float4 m  = *(float4*)&msg[eo * 128 + c];
            float4 g1 = *(const float4*)&G[j * 384 + 128 + c];
            float4 u  = *(const float4*)&G[j * 384 + 256 + c];
            m.x += gi.x + g1.x; m.y += gi.y + g1.y;
            m.z += gi.z + g1.z; m.w += gi.w + g1.w;
            *(float4*)&msg[eo * 128 + c] = m;
            float s0 = sigm(m.x), s1 = sigm(m.y), s2 = sigm(m.z), s3 = sigm(m.w);
            ssx += s0; ssy += s1; ssz += s2; ssw += s3;
            agx += s0 * u.x; agy += s1 * u.y; agz += s2 * u.z; agw += s3 * u.w;
            st1x += m.x; st1y += m.y; st1z += m.z; st1w += m.w;
            st2x += m.x * m.x; st2y += m.y * m.y; st2z += m.z * m.z; st2w += m.w * m.w;
        }
        float4 o;
        o.x = agx / (ssx + 1e-9f);
        o.y = agy / (ssy + 1e-9f);
        o.z = agz / (ssz + 1e-9f);
        o.w = agw / (ssw + 1e-9f);
        *(float4*)&agg[n * 128 + c] = o;
    }

    __shared__ float sred[2 * 8 * 128];
    float4 w1; w1.x = st1x; w1.y = st1y; w1.z = st1z; w1.w = st1w;
    float4 w2; w2.x = st2x; w2.y = st2y; w2.z = st2z; w2.w = st2w;
    *(float4*)&sred[sub * 128 + c] = w1;
    *(float4*)&sred[1024 + sub * 128 + c] = w2;
    __syncthreads();
    int tid = threadIdx.x;
    int col = tid & 127, which = tid >> 7;
    const float* bsrc = &sred[which * 1024 + col];
    float s = 0.f;
#pragma unroll
    for (int k = 0; k < 8; ++k) s += bsrc[k * 128];
    unsafeAtomicAdd(&stats[tid], s);
}

// column sums + sumsq over X[M,128] -> sums[0:128]=sum, sums[128:256]=sumsq
__global__ __launch_bounds__(256) void col_stats(
    const float* __restrict__ X, int M, float* __restrict__ sums)
{
    int col = threadIdx.x & 127, half = threadIdx.x >> 7;
    float s1 = 0.f, s2 = 0.f;
    for (long r = (long)blockIdx.x * 2 + half; r < M; r += (long)gridDim.x * 2) {
        float v = X[r * 128 + col];
        s1 += v; s2 += v * v;
    }
    __shared__ float red[512];
    red[threadIdx.x] = s1;
    red[256 + threadIdx.x] = s2;
    __syncthreads();
    if (threadIdx.x < 128) {
        unsafeAtomicAdd(&sums[col], red[threadIdx.x] + red[threadIdx.x + 128]);
        unsafeAtomicAdd(&sums[128 + col], red[256 + threadIdx.x] + red[256 + threadIdx.x + 128]);
    }
}

__global__ void bn_finalize(const float* __restrict__ sums,
                            const float* __restrict__ gamma, const float* __restrict__ beta,
                            float* __restrict__ sc, float* __restrict__ sh, float invM)
{
    int c = threadIdx.x;
    float mu = sums[c] * invM;
    float var = sums[128 + c] * invM - mu * mu;
    float inv = rsqrtf(var + 1e-5f);
    float s = gamma[c] * inv;
    sc[c] = s;
    sh[c] = beta[c] - mu * s;
}

// out = X + silu(scale*h + shift)   (out may alias X or h: same-index RMW)
__global__ __launch_bounds__(256) void node_final(
    const float* X, const float* h,
    const float* __restrict__ sc, const float* __restrict__ sh,
    float* out, long total4)
{
    long idx = (long)blockIdx.x * 256 + threadIdx.x;
    if (idx >= total4) return;
    int c = ((int)(idx & 31)) * 4;
    float4 xv = ((const float4*)X)[idx];
    float4 hv = ((const float4*)h)[idx];
    float4 scv = *(const float4*)&sc[c];
    float4 shv = *(const float4*)&sh[c];
    float b0 = scv.x * hv.x + shv.x, b1 = scv.y * hv.y + shv.y;
    float b2 = scv.z * hv.z + shv.z, b3 = scv.w * hv.w + shv.w;
    float4 o;
    o.x = xv.x + b0 * sigm(b0);
    o.y = xv.y + b1 * sigm(b1);
    o.z = xv.z + b2 * sigm(b2);
    o.w = xv.w + b3 * sigm(b3);
    ((float4*)out)[idx] = o;
}

// ---------------------------------------------------------------------------
static void run_conv(const int* idx, int Em, int Nn,
                     const float* X, const float* Efeat,
                     const float* W, const float* b,
                     const float* bng, const float* bnb,
                     float* msgbuf,    // [Em,128]: EW -> edge_msg -> e_out (in place)
                     float* x_out,     // [Nn,128] (may alias X)
                     float* G, float* agg, float* stats,
                     int* row_ptr, int* cursor, int* bsums, int2* pairs,
                     hipStream_t stream)
{
    const int* ii = idx;
    const int* jj = idx + Em;
    hipMemsetAsync(stats, 0, 1024 * 4, stream);
    hipMemsetAsync(cursor, 0, (size_t)Nn * 4, stream);

    // CSR build (cursor doubles as counts, then as write cursors)
    hist_k<<<(Em + 255) / 256, 256, 0, stream>>>(ii, cursor, Em);
    int nsb = (Nn + 1023) / 1024;
    scan_block<<<nsb, 256, 0, stream>>>(cursor, row_ptr, bsums, Nn);
    scan_bsums<<<1, 512, 0, stream>>>(bsums, nsb);
    add_off<<<(Nn + 1 + 255) / 256, 256, 0, stream>>>(row_ptr, bsums, cursor, Nn, Em);
    scatter_csr<<<(Em + 255) / 256, 256, 0, stream>>>(ii, jj, cursor, pairs, Em);

    int gN = (Nn + 63) / 64, gE = (Em + 63) / 64;
    // node projections: G[n] = [x@W0^T+b0 | x@W1^T+b1 | x@W4^T+b4]
    gemm_aw<<<gN, 256, 0, stream>>>(X, W + 0 * 16384, b + 0 * 128, nullptr, G + 0,   Nn, 384);
    gemm_aw<<<gN, 256, 0, stream>>>(X, W + 1 * 16384, b + 1 * 128, nullptr, G + 128, Nn, 384);
    gemm_aw<<<gN, 256, 0, stream>>>(X, W + 4 * 16384, b + 4 * 128, nullptr, G + 256, Nn, 384);
    // EW = e@W2^T + b2 into msg buffer
    gemm_aw<<<gE, 256, 0, stream>>>(Efeat, W + 2 * 16384, b + 2 * 128, nullptr, msgbuf, Em, 128);

    // fused finalize-msg + sigmoid-aggregate + BN stats (no atomics on big arrays)
    node_gather<<<2048, 256, 0, stream>>>(row_ptr, pairs, G, msgbuf, agg, stats, Nn);

    bn_finalize<<<1, 128, 0, stream>>>(stats, bng, bnb, stats + 256, stats + 384, 1.f / Em);
    long tE4 = (long)Em * 32;
    node_final<<<(int)((tE4 + 255) / 256), 256, 0, stream>>>(Efeat, msgbuf, stats + 256, stats + 384,
                                                             msgbuf, tE4);

    // h = X@W3^T + b3 + agg  (reuse G as h storage; G dead after node_gather)
    float* h = G;
    gemm_aw<<<gN, 256, 0, stream>>>(X, W + 3 * 16384, b + 3 * 128, agg, h, Nn, 128);
    col_stats<<<1024, 256, 0, stream>>>(h, Nn, stats + 512);
    bn_finalize<<<1, 128, 0, stream>>>(stats + 512, bng + 128, bnb + 128,
                                       stats + 768, stats + 896, 1.f / Nn);
    long tN4 = (long)Nn * 32;
    node_final<<<(int)((tN4 + 255) / 256), 256, 0, stream>>>(X, h, stats + 768, stats + 896,
                                                             x_out, tN4);
}

extern "C" void kernel_launch(void* const* d_in, const int* in_sizes, int n_in,
                              void* d_out, int out_size, void* d_ws, size_t ws_size,
                              hipStream_t stream)
{
    (void)in_sizes; (void)n_in; (void)out_size; (void)ws_size;
    const int*   g_idx  = (const int*)d_in[0];    // [2, 400000]
    const int*   lg_idx = (const int*)d_in[1];    // [2, 800000]
    const float* x   = (const float*)d_in[2];     // [50000,128]
    const float* y   = (const float*)d_in[3];     // [400000,128]
    const float* z   = (const float*)d_in[4];     // [800000,128]
    const float* W1  = (const float*)d_in[5];
    const float* b1  = (const float*)d_in[6];
    const float* bng1 = (const float*)d_in[7];
    const float* bnb1 = (const float*)d_in[8];
    const float* W2  = (const float*)d_in[9];
    const float* b2  = (const float*)d_in[10];
    const float* bng2 = (const float*)d_in[11];
    const float* bnb2 = (const float*)d_in[12];

    float* out   = (float*)d_out;
    float* x_out = out;                          // 50000*128
    float* y_reg = out + (long)50000 * 128;      // 400000*128: msg1 -> m -> y_out
    float* z_reg = y_reg + (long)400000 * 128;   // 800000*128: msg2 -> z_out

    float* G       = (float*)d_ws;               // 400000*384 floats
    float* agg     = G + (long)400000 * 384;     // 400000*128
    float* stats   = agg + (long)400000 * 128;   // 1024 floats
    int*   row_ptr = (int*)(stats + 1024);       // <=400001, reserve 400256
    int*   cursor  = row_ptr + 400256;           // counts -> cursors, reserve 400256
    int*   bsums   = cursor + 400256;            // <=512
    int2*  pairs   = (int2*)(bsums + 512);       // <=800000 (e, j) in CSR order

    // conv1 on graph g: (x, y) -> (x_out, m in y_reg)
    run_conv(g_idx, 400000, 50000, x, y, W1, b1, bng1, bnb1,
             y_reg, x_out, G, agg, stats, row_ptr, cursor, bsums, pairs, stream);
    // conv2 on line graph: nodes = edges of g (features m), edges = z
    run_conv(lg_idx, 800000, 400000, y_reg, z, W2, b2, bng2, bnb2,
             z_reg, y_reg, G, agg, stats, row_ptr, cursor, bsums, pairs, stream);
}